// Round 9
// baseline (5408.037 us; speedup 1.0000x reference)
//
#include <hip/hip_runtime.h>

typedef __attribute__((ext_vector_type(8))) short s16x8;
typedef __attribute__((ext_vector_type(4))) float f32x4;

#define SCOPE_AGENT __HIP_MEMORY_SCOPE_AGENT

static __device__ __forceinline__ unsigned short f2bf(float f) {
    unsigned u = __float_as_uint(f);
    u = (u + 0x7fffu + ((u >> 16) & 1u)) >> 16;
    return (unsigned short)u;
}

static __device__ __forceinline__ unsigned ld_sc1(const unsigned* p) {
    return __hip_atomic_load(p, __ATOMIC_RELAXED, SCOPE_AGENT);
}
static __device__ __forceinline__ void st_sc1(unsigned* p, unsigned v) {
    __hip_atomic_store(p, v, __ATOMIC_RELAXED, SCOPE_AGENT);
}

__global__ void k_cast_bf16(const float* __restrict__ src,
                            unsigned short* __restrict__ dst, int n4) {
    int i = blockIdx.x * blockDim.x + threadIdx.x;
    int stride = gridDim.x * blockDim.x;
    for (; i < n4; i += stride) {
        float4 v = reinterpret_cast<const float4*>(src)[i];
        ushort4 o;
        o.x = f2bf(v.x); o.y = f2bf(v.y); o.z = f2bf(v.z); o.w = f2bf(v.w);
        reinterpret_cast<ushort4*>(dst)[i] = o;
    }
}

// Persistent GRU: 256 blocks x 256 threads (4 waves). Block (rb, jt):
// batch rows [rb*64,+64), hidden cols [jt*16,+16). Weights in LDS
// (147KB, 4-bit XOR swizzle, conflict-free). Flat flag sync (r8).
// Round 9 changes:
//  (1) xfn loads moved POST-flag into the x-phase: the 16MB/step 64x-
//      redundant x read burst leaves the latency-critical flag window,
//      lands after this WG's inv (L2 reuse can work), and the pre-flag
//      vmcnt drain no longer waits on it.
//  (2) split-wait: wave0 polls flags[0..31] -> barrier -> all load k<512
//      h frags; waves1-3 run first-half MFMAs while wave0 polls
//      flags[32..63] -> barrier -> second half. Straggler tail hides
//      under real compute. (granule kk covers k=kk*32+lk*8: kk<16 <->
//      producers jt 0..31 exactly.)
__global__ __launch_bounds__(256, 1) void k_gru(
    const unsigned short* __restrict__ x16,    // [256][512][512] bf16
    const unsigned short* __restrict__ wh,     // [3][1024][1024]
    const unsigned short* __restrict__ wx,     // [3][1024][512]
    const unsigned short* __restrict__ wo,     // [512][1024]
    const float* __restrict__ bxr_, const float* __restrict__ bhr_,
    const float* __restrict__ bxc_, const float* __restrict__ bhc_,
    const float* __restrict__ bxz_, const float* __restrict__ bhz_,
    const float* __restrict__ bo_,
    unsigned short* __restrict__ h16a,         // [256][1024] bf16, zeroed
    unsigned short* __restrict__ h16b,
    unsigned* __restrict__ slots,              // [4][64] monotone flags, zeroed
    float* __restrict__ out)                   // [256][512]
{
    extern __shared__ unsigned short lds[];

    const int tid = threadIdx.x;
    const int bid = blockIdx.x;
    const int xcd = bid & 7;
    const int rb  = xcd >> 1;
    const int jt  = ((bid >> 3) << 1) | (xcd & 1);
    const int b0  = rb * 64;
    const int j0  = jt * 16;

    // ---- stage weight tile into LDS once (4-bit XOR swizzle) ----
    for (int i = 0; i < 36; ++i) {
        int gidx = i * 256 + tid;
        int rr = gidx / 192;
        int gc = gidx - rr * 192;
        int k  = gc << 3;
        int gate = rr >> 4;
        int j = j0 + (rr & 15);
        const unsigned short* src =
            (k < 1024) ? (wh + ((size_t)gate << 20) + ((size_t)j << 10) + k)
                       : (wx + (size_t)gate * 524288 + ((size_t)j << 9) + (k - 1024));
        s16x8 v = *reinterpret_cast<const s16x8*>(src);
        int boff = ((rr * 192 + gc) << 4) ^ ((rr & 15) << 4);
        *reinterpret_cast<s16x8*>(reinterpret_cast<char*>(lds) + boff) = v;
    }
    __syncthreads();

    const int lane = tid & 63;
    const int wv   = tid >> 6;
    const int l15  = lane & 15;
    const int lk   = lane >> 4;

    const int b   = b0 + wv * 16 + l15;
    const int jq  = j0 + lk * 4;
    const int swz = l15 << 4;
    const int rbase0 = (l15)      * 192 + lk;
    const int rbase1 = (16 + l15) * 192 + lk;
    const int rbase2 = (32 + l15) * 192 + lk;

    float bR[4], bZ[4], bCh[4], bCx[4];
#pragma unroll
    for (int e = 0; e < 4; ++e) {
        int j = jq + e;
        bR[e]  = bxr_[j] + bhr_[j];
        bZ[e]  = bxz_[j] + bhz_[j];
        bCh[e] = bhc_[j];
        bCx[e] = bxc_[j];
    }

    float hreg[4] = {0.f, 0.f, 0.f, 0.f};
    char* lb = reinterpret_cast<char*>(lds);
    const unsigned short* xrowbase = x16 + (size_t)b * 262144 + lk * 8;
    unsigned* myflag  = &slots[(rb << 6) + jt];
    unsigned* gflags  = &slots[rb << 6];

    // ---- prologue: x-part accumulators for t=0 ----
    f32x4 xR = {0.f,0.f,0.f,0.f}, xZ = {0.f,0.f,0.f,0.f}, xC = {0.f,0.f,0.f,0.f};
    {
        s16x8 xf[16];
#pragma unroll
        for (int kk = 0; kk < 16; ++kk)
            xf[kk] = *reinterpret_cast<const s16x8*>(xrowbase + kk * 32);
#pragma unroll
        for (int kk = 0; kk < 16; ++kk) {
            s16x8 w0 = *reinterpret_cast<s16x8*>(lb + (((rbase0 + (kk + 32) * 4) << 4) ^ swz));
            s16x8 w1 = *reinterpret_cast<s16x8*>(lb + (((rbase1 + (kk + 32) * 4) << 4) ^ swz));
            s16x8 w2 = *reinterpret_cast<s16x8*>(lb + (((rbase2 + (kk + 32) * 4) << 4) ^ swz));
            xR = __builtin_amdgcn_mfma_f32_16x16x32_bf16(w0, xf[kk], xR, 0, 0, 0);
            xC = __builtin_amdgcn_mfma_f32_16x16x32_bf16(w1, xf[kk], xC, 0, 0, 0);
            xZ = __builtin_amdgcn_mfma_f32_16x16x32_bf16(w2, xf[kk], xZ, 0, 0, 0);
        }
    }

    unsigned short* hc = h16a;                 // holds h_t (h_0 zeroed)
    unsigned short* hn = h16b;

    for (int t = 0; t < 512; ++t) {
        const unsigned tgt = (unsigned)t;
        // ---- phase 1: wave0 polls first-half flags (producers of k<512) ----
        if (wv == 0) {
            for (;;) {
                unsigned v = ld_sc1(&gflags[lane & 31]);
                if (__all((int)(v >= tgt))) break;
                __builtin_amdgcn_s_sleep(1);
            }
        }
        __syncthreads();
        asm volatile("" ::: "memory");

        // all waves: load first-half h fragments (k < 512)
        s16x8 hf[16];
        const unsigned short* hrow = hc + ((size_t)b << 10) + lk * 8;
#pragma unroll
        for (int kk = 0; kk < 16; ++kk)
            hf[kk] = *reinterpret_cast<const s16x8*>(hrow + kk * 32);

        f32x4 aR = xR, aZ = xZ, aCx = xC;
        f32x4 aCh = {0.f,0.f,0.f,0.f};

        if (wv != 0) {
            // waves 1-3: first-half MFMAs while wave0 polls half-2
#pragma unroll
            for (int kk = 0; kk < 16; ++kk) {
                s16x8 w0 = *reinterpret_cast<s16x8*>(lb + (((rbase0 + kk * 4) << 4) ^ swz));
                s16x8 w1 = *reinterpret_cast<s16x8*>(lb + (((rbase1 + kk * 4) << 4) ^ swz));
                s16x8 w2 = *reinterpret_cast<s16x8*>(lb + (((rbase2 + kk * 4) << 4) ^ swz));
                aR  = __builtin_amdgcn_mfma_f32_16x16x32_bf16(w0, hf[kk], aR, 0, 0, 0);
                aCh = __builtin_amdgcn_mfma_f32_16x16x32_bf16(w1, hf[kk], aCh, 0, 0, 0);
                aZ  = __builtin_amdgcn_mfma_f32_16x16x32_bf16(w2, hf[kk], aZ, 0, 0, 0);
            }
        } else {
            // wave0: poll second-half flags (producers of k >= 512)
            for (;;) {
                unsigned v = ld_sc1(&gflags[32 + (lane & 31)]);
                if (__all((int)(v >= tgt))) break;
                __builtin_amdgcn_s_sleep(1);
            }
        }
        __syncthreads();
        asm volatile("" ::: "memory");

        // all waves: load second-half h fragments (k >= 512)
        s16x8 hg[16];
#pragma unroll
        for (int kk = 0; kk < 16; ++kk)
            hg[kk] = *reinterpret_cast<const s16x8*>(hrow + (kk + 16) * 32);

        if (wv == 0) {
            // wave0 catches up on first-half MFMAs
#pragma unroll
            for (int kk = 0; kk < 16; ++kk) {
                s16x8 w0 = *reinterpret_cast<s16x8*>(lb + (((rbase0 + kk * 4) << 4) ^ swz));
                s16x8 w1 = *reinterpret_cast<s16x8*>(lb + (((rbase1 + kk * 4) << 4) ^ swz));
                s16x8 w2 = *reinterpret_cast<s16x8*>(lb + (((rbase2 + kk * 4) << 4) ^ swz));
                aR  = __builtin_amdgcn_mfma_f32_16x16x32_bf16(w0, hf[kk], aR, 0, 0, 0);
                aCh = __builtin_amdgcn_mfma_f32_16x16x32_bf16(w1, hf[kk], aCh, 0, 0, 0);
                aZ  = __builtin_amdgcn_mfma_f32_16x16x32_bf16(w2, hf[kk], aZ, 0, 0, 0);
            }
        }
        // all waves: second-half MFMAs
#pragma unroll
        for (int kk = 16; kk < 32; ++kk) {
            s16x8 w0 = *reinterpret_cast<s16x8*>(lb + (((rbase0 + kk * 4) << 4) ^ swz));
            s16x8 w1 = *reinterpret_cast<s16x8*>(lb + (((rbase1 + kk * 4) << 4) ^ swz));
            s16x8 w2 = *reinterpret_cast<s16x8*>(lb + (((rbase2 + kk * 4) << 4) ^ swz));
            aR  = __builtin_amdgcn_mfma_f32_16x16x32_bf16(w0, hg[kk - 16], aR, 0, 0, 0);
            aCh = __builtin_amdgcn_mfma_f32_16x16x32_bf16(w1, hg[kk - 16], aCh, 0, 0, 0);
            aZ  = __builtin_amdgcn_mfma_f32_16x16x32_bf16(w2, hg[kk - 16], aZ, 0, 0, 0);
        }

        // ---- gate math; store own h_{t+1} (sc1 -> MALL, bypasses L2) ----
        unsigned long long pack = 0ull;
#pragma unroll
        for (int e = 0; e < 4; ++e) {
            float r   = __builtin_amdgcn_rcpf(1.f + __expf(-(aR[e] + bR[e])));
            float zg  = __builtin_amdgcn_rcpf(1.f + __expf(-(aZ[e] + bZ[e])));
            float u2  = aCx[e] + bCx[e] + r * (aCh[e] + bCh[e]);
            float cg  = 1.f - 2.f * __builtin_amdgcn_rcpf(__expf(2.f * u2) + 1.f);
            float hnv = (1.f - zg) * hreg[e] + zg * cg;
            hreg[e] = hnv;
            pack |= (unsigned long long)f2bf(hnv) << (16 * e);
        }
        __hip_atomic_store(
            reinterpret_cast<unsigned long long*>(hn + ((size_t)b << 10) + jq),
            pack, __ATOMIC_RELAXED, SCOPE_AGENT);

        __syncthreads();   // drains vmcnt(0): only the h store now (xfn gone)
        if (tid == 0) {
            st_sc1(myflag, (unsigned)(t + 1));
            // early ACQUIRE-inv (L1+L2), strictly before next-step loads
            (void)__hip_atomic_load(myflag, __ATOMIC_ACQUIRE, SCOPE_AGENT);
        }

        // ---- x-phase for t+1 (post-flag window): load x, then MFMAs ----
        if (t < 511) {
            s16x8 xfn[16];
            const unsigned short* axn = xrowbase + (size_t)(t + 1) * 512;
#pragma unroll
            for (int kk = 0; kk < 16; ++kk)
                xfn[kk] = *reinterpret_cast<const s16x8*>(axn + kk * 32);
            xR = {0.f,0.f,0.f,0.f}; xZ = {0.f,0.f,0.f,0.f}; xC = {0.f,0.f,0.f,0.f};
#pragma unroll
            for (int kk = 0; kk < 16; ++kk) {
                s16x8 w0 = *reinterpret_cast<s16x8*>(lb + (((rbase0 + (kk + 32) * 4) << 4) ^ swz));
                s16x8 w1 = *reinterpret_cast<s16x8*>(lb + (((rbase1 + (kk + 32) * 4) << 4) ^ swz));
                s16x8 w2 = *reinterpret_cast<s16x8*>(lb + (((rbase2 + (kk + 32) * 4) << 4) ^ swz));
                xR = __builtin_amdgcn_mfma_f32_16x16x32_bf16(w0, xfn[kk], xR, 0, 0, 0);
                xC = __builtin_amdgcn_mfma_f32_16x16x32_bf16(w1, xfn[kk], xC, 0, 0, 0);
                xZ = __builtin_amdgcn_mfma_f32_16x16x32_bf16(w2, xfn[kk], xZ, 0, 0, 0);
            }
        }

        unsigned short* tmp = hc; hc = hn; hn = tmp;
    }

    // ---- wait for full h_512, then output projection ----
    if (wv == 0) {
        for (;;) {
            unsigned v = ld_sc1(&gflags[lane]);
            if (__all((int)(v >= 512u))) break;
            __builtin_amdgcn_s_sleep(1);
        }
        if (tid == 0)
            (void)__hip_atomic_load(myflag, __ATOMIC_ACQUIRE, SCOPE_AGENT);
    }
    __syncthreads();
    asm volatile("" ::: "memory");

    const int ocol  = jt * 8 + l15;
    const int ocolc = (l15 < 8) ? ocol : (jt * 8 + 7);
    f32x4 aO = {0.f,0.f,0.f,0.f};
    const unsigned short* hrow = hc + ((size_t)b << 10) + lk * 8;
    const unsigned short* bw = wo + ((size_t)ocolc << 10) + lk * 8;
#pragma unroll
    for (int kk = 0; kk < 32; ++kk) {
        s16x8 hv = *reinterpret_cast<const s16x8*>(hrow + kk * 32);
        s16x8 wb = *reinterpret_cast<const s16x8*>(bw + kk * 32);
        aO = __builtin_amdgcn_mfma_f32_16x16x32_bf16(hv, wb, aO, 0, 0, 0);
    }
    if (l15 < 8) {
        const float bov = bo_[ocol];
#pragma unroll
        for (int e = 0; e < 4; ++e) {
            out[((size_t)(b0 + wv * 16 + lk * 4 + e) << 9) + ocol] = aO[e] + bov;
        }
    }
}

extern "C" void kernel_launch(void* const* d_in, const int* in_sizes, int n_in,
                              void* d_out, int out_size, void* d_ws, size_t ws_size,
                              hipStream_t stream) {
    const float* x   = (const float*)d_in[0];
    const float* Wxr = (const float*)d_in[1];
    const float* bxr = (const float*)d_in[2];
    const float* Whr = (const float*)d_in[3];
    const float* bhr = (const float*)d_in[4];
    const float* Wxc = (const float*)d_in[5];
    const float* bxc = (const float*)d_in[6];
    const float* Whc = (const float*)d_in[7];
    const float* bhc = (const float*)d_in[8];
    const float* Wxz = (const float*)d_in[9];
    const float* bxz = (const float*)d_in[10];
    const float* Whz = (const float*)d_in[11];
    const float* bhz = (const float*)d_in[12];
    const float* Wo  = (const float*)d_in[13];
    const float* bo  = (const float*)d_in[14];

    char* ws = (char*)d_ws;
    unsigned short* x16  = (unsigned short*)(ws);                // 134217728 B
    unsigned short* wh   = (unsigned short*)(ws + 134217728);    //   6291456 B
    unsigned short* wx   = (unsigned short*)(ws + 140509184);    //   3145728 B
    unsigned short* wo16 = (unsigned short*)(ws + 143654912);    //   1048576 B
    unsigned short* h16a = (unsigned short*)(ws + 144703488);    //    524288 B
    unsigned short* h16b = (unsigned short*)(ws + 145227776);    //    524288 B
    unsigned*       slots= (unsigned*)(ws + 145752064);          //      1024 B

    auto cast = [&](const float* s, unsigned short* d, int n) {
        int n4 = n >> 2;
        int blocks = (n4 + 255) / 256;
        if (blocks > 4096) blocks = 4096;
        k_cast_bf16<<<blocks, 256, 0, stream>>>(s, d, n4);
    };
    cast(x,   x16, 67108864);
    cast(Whr, wh,            1048576);
    cast(Whc, wh + 1048576,  1048576);
    cast(Whz, wh + 2097152,  1048576);
    cast(Wxr, wx,            524288);
    cast(Wxc, wx + 524288,   524288);
    cast(Wxz, wx + 1048576,  524288);
    cast(Wo,  wo16,          524288);

    hipMemsetAsync(h16a, 0, 524288, stream);
    hipMemsetAsync(slots, 0, 1024, stream);

    hipFuncSetAttribute(reinterpret_cast<const void*>(k_gru),
                        hipFuncAttributeMaxDynamicSharedMemorySize, 147456);
    k_gru<<<dim3(256), dim3(256), 147456, stream>>>(
        x16, wh, wx, wo16, bxr, bhr, bxc, bhc, bxz, bhz, bo,
        h16a, h16b, slots, (float*)d_out);
}

// Round 10
// 3885.362 us; speedup vs baseline: 1.3919x; 1.3919x over previous
//
#include <hip/hip_runtime.h>

typedef __attribute__((ext_vector_type(8))) short s16x8;
typedef __attribute__((ext_vector_type(4))) float f32x4;

#define SCOPE_AGENT __HIP_MEMORY_SCOPE_AGENT

static __device__ __forceinline__ unsigned short f2bf(float f) {
    unsigned u = __float_as_uint(f);
    u = (u + 0x7fffu + ((u >> 16) & 1u)) >> 16;
    return (unsigned short)u;
}

static __device__ __forceinline__ unsigned ld_sc1(const unsigned* p) {
    return __hip_atomic_load(p, __ATOMIC_RELAXED, SCOPE_AGENT);
}
static __device__ __forceinline__ void st_sc1(unsigned* p, unsigned v) {
    __hip_atomic_store(p, v, __ATOMIC_RELAXED, SCOPE_AGENT);
}

__global__ void k_cast_bf16(const float* __restrict__ src,
                            unsigned short* __restrict__ dst, int n4) {
    int i = blockIdx.x * blockDim.x + threadIdx.x;
    int stride = gridDim.x * blockDim.x;
    for (; i < n4; i += stride) {
        float4 v = reinterpret_cast<const float4*>(src)[i];
        ushort4 o;
        o.x = f2bf(v.x); o.y = f2bf(v.y); o.z = f2bf(v.z); o.w = f2bf(v.w);
        reinterpret_cast<ushort4*>(dst)[i] = o;
    }
}

// Persistent GRU: 256 blocks x 256 threads (4 waves). Block (rb, jt):
// batch rows [rb*64,+64), hidden cols [jt*16,+16). Weights in LDS
// (147KB, 4-bit XOR swizzle, conflict-free). Flat flag sync (r8).
// Round 10 change (single lever): h ping-pong pair -> RING OF 8 buffers,
// and the per-step acquire-inv is replaced by ONE inv per 8 steps
// (tid0, post-detect, at t % 8 == 0). Guarantee: an h line cached at
// step u is invalidated at the unique multiple-of-8 in (u, u+8], which
// precedes its next read at u+8. The other 7 steps run inv-free, so
// x lines are fetched once per XCD and shared, and h lines fill L2 once
// for all 32 WGs on the XCD (no mid-step cache wipes).
__global__ __launch_bounds__(256, 1) void k_gru(
    const unsigned short* __restrict__ x16,    // [256][512][512] bf16
    const unsigned short* __restrict__ wh,     // [3][1024][1024]
    const unsigned short* __restrict__ wx,     // [3][1024][512]
    const unsigned short* __restrict__ wo,     // [512][1024]
    const float* __restrict__ bxr_, const float* __restrict__ bhr_,
    const float* __restrict__ bxc_, const float* __restrict__ bhc_,
    const float* __restrict__ bxz_, const float* __restrict__ bhz_,
    const float* __restrict__ bo_,
    unsigned short* __restrict__ hring,        // 8 x [256][1024] bf16; buf0 zeroed
    unsigned* __restrict__ slots,              // [4][64] monotone flags, zeroed
    float* __restrict__ out)                   // [256][512]
{
    extern __shared__ unsigned short lds[];

    const int tid = threadIdx.x;
    const int bid = blockIdx.x;
    const int xcd = bid & 7;
    const int rb  = xcd >> 1;
    const int jt  = ((bid >> 3) << 1) | (xcd & 1);
    const int b0  = rb * 64;
    const int j0  = jt * 16;

    // ---- stage weight tile into LDS once (4-bit XOR swizzle) ----
    for (int i = 0; i < 36; ++i) {
        int gidx = i * 256 + tid;
        int rr = gidx / 192;
        int gc = gidx - rr * 192;
        int k  = gc << 3;
        int gate = rr >> 4;
        int j = j0 + (rr & 15);
        const unsigned short* src =
            (k < 1024) ? (wh + ((size_t)gate << 20) + ((size_t)j << 10) + k)
                       : (wx + (size_t)gate * 524288 + ((size_t)j << 9) + (k - 1024));
        s16x8 v = *reinterpret_cast<const s16x8*>(src);
        int boff = ((rr * 192 + gc) << 4) ^ ((rr & 15) << 4);
        *reinterpret_cast<s16x8*>(reinterpret_cast<char*>(lds) + boff) = v;
    }
    __syncthreads();

    const int lane = tid & 63;
    const int wv   = tid >> 6;
    const int l15  = lane & 15;
    const int lk   = lane >> 4;

    const int b   = b0 + wv * 16 + l15;
    const int jq  = j0 + lk * 4;
    const int swz = l15 << 4;
    const int rbase0 = (l15)      * 192 + lk;
    const int rbase1 = (16 + l15) * 192 + lk;
    const int rbase2 = (32 + l15) * 192 + lk;

    float bR[4], bZ[4], bCh[4], bCx[4];
#pragma unroll
    for (int e = 0; e < 4; ++e) {
        int j = jq + e;
        bR[e]  = bxr_[j] + bhr_[j];
        bZ[e]  = bxz_[j] + bhz_[j];
        bCh[e] = bhc_[j];
        bCx[e] = bxc_[j];
    }

    float hreg[4] = {0.f, 0.f, 0.f, 0.f};
    char* lb = reinterpret_cast<char*>(lds);
    const unsigned short* xrowbase = x16 + (size_t)b * 262144 + lk * 8;
    unsigned* myflag  = &slots[(rb << 6) + jt];
    unsigned* gflags  = &slots[rb << 6];

    // ---- prologue: x-part accumulators for t=0 ----
    f32x4 xR = {0.f,0.f,0.f,0.f}, xZ = {0.f,0.f,0.f,0.f}, xC = {0.f,0.f,0.f,0.f};
    {
        s16x8 xf[16];
#pragma unroll
        for (int kk = 0; kk < 16; ++kk)
            xf[kk] = *reinterpret_cast<const s16x8*>(xrowbase + kk * 32);
#pragma unroll
        for (int kk = 0; kk < 16; ++kk) {
            s16x8 w0 = *reinterpret_cast<s16x8*>(lb + (((rbase0 + (kk + 32) * 4) << 4) ^ swz));
            s16x8 w1 = *reinterpret_cast<s16x8*>(lb + (((rbase1 + (kk + 32) * 4) << 4) ^ swz));
            s16x8 w2 = *reinterpret_cast<s16x8*>(lb + (((rbase2 + (kk + 32) * 4) << 4) ^ swz));
            xR = __builtin_amdgcn_mfma_f32_16x16x32_bf16(w0, xf[kk], xR, 0, 0, 0);
            xC = __builtin_amdgcn_mfma_f32_16x16x32_bf16(w1, xf[kk], xC, 0, 0, 0);
            xZ = __builtin_amdgcn_mfma_f32_16x16x32_bf16(w2, xf[kk], xZ, 0, 0, 0);
        }
    }

    for (int t = 0; t < 512; ++t) {
        const unsigned short* hc = hring + (size_t)(t & 7) * 262144;       // h_t
        unsigned short*       hn = hring + (size_t)((t + 1) & 7) * 262144; // h_{t+1}

        // ---- wait for h_t: wave0 polls ALL 64 group flags directly ----
        if (wv == 0) {
            const unsigned tgt = (unsigned)t;
            for (;;) {
                unsigned v = ld_sc1(&gflags[lane]);
                if (__all((int)(v >= tgt))) break;
                __builtin_amdgcn_s_sleep(1);
            }
        }
        // ---- boundary inv: once per 8 steps, before any h load ----
        if ((t & 7) == 0 && tid == 0)
            (void)__hip_atomic_load(myflag, __ATOMIC_ACQUIRE, SCOPE_AGENT);
        __syncthreads();
        asm volatile("" ::: "memory");

        // ---- load h_t fragments: NORMAL cached 16B loads (L2-shared) ----
        s16x8 hf[32];
        const unsigned short* hrow = hc + ((size_t)b << 10) + lk * 8;
#pragma unroll
        for (int kk = 0; kk < 32; ++kk)
            hf[kk] = *reinterpret_cast<const s16x8*>(hrow + kk * 32);

        // ---- prefetch x fragments for t+1 (consumed post-barrier) ----
        s16x8 xfn[16];
        if (t < 511) {
            const unsigned short* axn = xrowbase + (size_t)(t + 1) * 512;
#pragma unroll
            for (int kk = 0; kk < 16; ++kk)
                xfn[kk] = *reinterpret_cast<const s16x8*>(axn + kk * 32);
        }

        // ---- h-part MFMAs, accs seeded from x-part ----
        f32x4 aR = xR, aZ = xZ, aCx = xC;
        f32x4 aCh = {0.f,0.f,0.f,0.f};
#pragma unroll
        for (int kk = 0; kk < 32; ++kk) {
            s16x8 w0 = *reinterpret_cast<s16x8*>(lb + (((rbase0 + kk * 4) << 4) ^ swz));
            s16x8 w1 = *reinterpret_cast<s16x8*>(lb + (((rbase1 + kk * 4) << 4) ^ swz));
            s16x8 w2 = *reinterpret_cast<s16x8*>(lb + (((rbase2 + kk * 4) << 4) ^ swz));
            aR  = __builtin_amdgcn_mfma_f32_16x16x32_bf16(w0, hf[kk], aR, 0, 0, 0);
            aCh = __builtin_amdgcn_mfma_f32_16x16x32_bf16(w1, hf[kk], aCh, 0, 0, 0);
            aZ  = __builtin_amdgcn_mfma_f32_16x16x32_bf16(w2, hf[kk], aZ, 0, 0, 0);
        }

        // ---- gate math; store own h_{t+1} (sc1 -> MALL, bypasses L2) ----
        unsigned long long pack = 0ull;
#pragma unroll
        for (int e = 0; e < 4; ++e) {
            float r   = __builtin_amdgcn_rcpf(1.f + __expf(-(aR[e] + bR[e])));
            float zg  = __builtin_amdgcn_rcpf(1.f + __expf(-(aZ[e] + bZ[e])));
            float u2  = aCx[e] + bCx[e] + r * (aCh[e] + bCh[e]);
            float cg  = 1.f - 2.f * __builtin_amdgcn_rcpf(__expf(2.f * u2) + 1.f);
            float hnv = (1.f - zg) * hreg[e] + zg * cg;
            hreg[e] = hnv;
            pack |= (unsigned long long)f2bf(hnv) << (16 * e);
        }
        __hip_atomic_store(
            reinterpret_cast<unsigned long long*>(hn + ((size_t)b << 10) + jq),
            pack, __ATOMIC_RELAXED, SCOPE_AGENT);

        __syncthreads();   // drains vmcnt(0): h store + xfn loads complete
        if (tid == 0)
            st_sc1(myflag, (unsigned)(t + 1));   // flag only; no per-step inv

        // ---- x-part MFMAs for t+1 (overlaps peers' flag propagation) ----
        if (t < 511) {
            xR = {0.f,0.f,0.f,0.f}; xZ = {0.f,0.f,0.f,0.f}; xC = {0.f,0.f,0.f,0.f};
#pragma unroll
            for (int kk = 0; kk < 16; ++kk) {
                s16x8 w0 = *reinterpret_cast<s16x8*>(lb + (((rbase0 + (kk + 32) * 4) << 4) ^ swz));
                s16x8 w1 = *reinterpret_cast<s16x8*>(lb + (((rbase1 + (kk + 32) * 4) << 4) ^ swz));
                s16x8 w2 = *reinterpret_cast<s16x8*>(lb + (((rbase2 + (kk + 32) * 4) << 4) ^ swz));
                xR = __builtin_amdgcn_mfma_f32_16x16x32_bf16(w0, xfn[kk], xR, 0, 0, 0);
                xC = __builtin_amdgcn_mfma_f32_16x16x32_bf16(w1, xfn[kk], xC, 0, 0, 0);
                xZ = __builtin_amdgcn_mfma_f32_16x16x32_bf16(w2, xfn[kk], xZ, 0, 0, 0);
            }
        }
    }

    // ---- wait for full h_512, then output projection ----
    if (wv == 0) {
        for (;;) {
            unsigned v = ld_sc1(&gflags[lane]);
            if (__all((int)(v >= 512u))) break;
            __builtin_amdgcn_s_sleep(1);
        }
        if (tid == 0)
            (void)__hip_atomic_load(myflag, __ATOMIC_ACQUIRE, SCOPE_AGENT);
    }
    __syncthreads();
    asm volatile("" ::: "memory");

    const unsigned short* hfin = hring;        // h_512 lives in buffer 0
    const int ocol  = jt * 8 + l15;
    const int ocolc = (l15 < 8) ? ocol : (jt * 8 + 7);
    f32x4 aO = {0.f,0.f,0.f,0.f};
    const unsigned short* hrow = hfin + ((size_t)b << 10) + lk * 8;
    const unsigned short* bw = wo + ((size_t)ocolc << 10) + lk * 8;
#pragma unroll
    for (int kk = 0; kk < 32; ++kk) {
        s16x8 hv = *reinterpret_cast<const s16x8*>(hrow + kk * 32);
        s16x8 wb = *reinterpret_cast<const s16x8*>(bw + kk * 32);
        aO = __builtin_amdgcn_mfma_f32_16x16x32_bf16(hv, wb, aO, 0, 0, 0);
    }
    if (l15 < 8) {
        const float bov = bo_[ocol];
#pragma unroll
        for (int e = 0; e < 4; ++e) {
            out[((size_t)(b0 + wv * 16 + lk * 4 + e) << 9) + ocol] = aO[e] + bov;
        }
    }
}

extern "C" void kernel_launch(void* const* d_in, const int* in_sizes, int n_in,
                              void* d_out, int out_size, void* d_ws, size_t ws_size,
                              hipStream_t stream) {
    const float* x   = (const float*)d_in[0];
    const float* Wxr = (const float*)d_in[1];
    const float* bxr = (const float*)d_in[2];
    const float* Whr = (const float*)d_in[3];
    const float* bhr = (const float*)d_in[4];
    const float* Wxc = (const float*)d_in[5];
    const float* bxc = (const float*)d_in[6];
    const float* Whc = (const float*)d_in[7];
    const float* bhc = (const float*)d_in[8];
    const float* Wxz = (const float*)d_in[9];
    const float* bxz = (const float*)d_in[10];
    const float* Whz = (const float*)d_in[11];
    const float* bhz = (const float*)d_in[12];
    const float* Wo  = (const float*)d_in[13];
    const float* bo  = (const float*)d_in[14];

    char* ws = (char*)d_ws;
    unsigned short* x16  = (unsigned short*)(ws);                // 134217728 B
    unsigned short* wh   = (unsigned short*)(ws + 134217728);    //   6291456 B
    unsigned short* wx   = (unsigned short*)(ws + 140509184);    //   3145728 B
    unsigned short* wo16 = (unsigned short*)(ws + 143654912);    //   1048576 B
    unsigned short* hring= (unsigned short*)(ws + 144703488);    // 8x524288 B
    unsigned*       slots= (unsigned*)(ws + 148897792);          //      1024 B

    auto cast = [&](const float* s, unsigned short* d, int n) {
        int n4 = n >> 2;
        int blocks = (n4 + 255) / 256;
        if (blocks > 4096) blocks = 4096;
        k_cast_bf16<<<blocks, 256, 0, stream>>>(s, d, n4);
    };
    cast(x,   x16, 67108864);
    cast(Whr, wh,            1048576);
    cast(Whc, wh + 1048576,  1048576);
    cast(Whz, wh + 2097152,  1048576);
    cast(Wxr, wx,            524288);
    cast(Wxc, wx + 524288,   524288);
    cast(Wxz, wx + 1048576,  524288);
    cast(Wo,  wo16,          524288);

    hipMemsetAsync(hring, 0, 524288, stream);   // buffer 0 = h_0 = 0
    hipMemsetAsync(slots, 0, 1024, stream);

    hipFuncSetAttribute(reinterpret_cast<const void*>(k_gru),
                        hipFuncAttributeMaxDynamicSharedMemorySize, 147456);
    k_gru<<<dim3(256), dim3(256), 147456, stream>>>(
        x16, wh, wx, wo16, bxr, bhr, bxc, bhc, bxz, bhz, bo,
        hring, slots, (float*)d_out);
}